// Round 9
// baseline (115.187 us; speedup 1.0000x reference)
//
#include <hip/hip_runtime.h>
#include <cstdint>
#include <cstddef>

#define DZc   128
#define Lc    256
#define Hc    4
#define DCc   32
#define DHCc  128
#define NPOSc (Lc * Lc)

typedef __attribute__((ext_vector_type(8))) short bf16x8;
typedef __attribute__((ext_vector_type(4))) short bf16x4;
typedef __attribute__((ext_vector_type(4))) float f32x4;

static __device__ __forceinline__ unsigned short f2bf(float f) {
  unsigned u = __float_as_uint(f);
  u += 0x7FFFu + ((u >> 16) & 1u);     // round-to-nearest-even
  return (unsigned short)(u >> 16);
}
static __device__ __forceinline__ float bf2f(unsigned short h) {
  return __uint_as_float(((unsigned)h) << 16);
}
static __device__ __forceinline__ float sigmoidf_(float x) {
  return 1.0f / (1.0f + __expf(-x));
}

// ---------------------------------------------------------------------------
// prep: weights fp32 [k][j] -> bf16 transposed [j][k]; q-scale folded into wq.
// slot 0..3 = wq,wk,wv,wg ; slot 4 = w2 (-> w2T[c][k]).
// ---------------------------------------------------------------------------
__global__ __launch_bounds__(256) void prep_weights(
    const float* __restrict__ wq, const float* __restrict__ wk,
    const float* __restrict__ wv, const float* __restrict__ wg,
    const float* __restrict__ w2, unsigned short* __restrict__ wT)
{
  const int b = blockIdx.x;  // 0..4
  const int t = threadIdx.x;
  const float* src = (b == 0) ? wq : (b == 1) ? wk : (b == 2) ? wv : (b == 3) ? wg : w2;
  unsigned short* dst = wT + (size_t)b * (DZc * DHCc);
  const float scale = (b == 0) ? 0.17677669529663687f : 1.0f;  // sqrt(1/32)
  for (int p = 0; p < 64; ++p) {
    const int idx = p * 256 + t;             // 16384 elements
    const int kk = idx >> 7, j = idx & 127;  // src[kk][j]
    dst[j * 128 + kk] = f2bf(src[idx] * scale);
  }
}

// ---------------------------------------------------------------------------
// K1 v6: LN (in-register stats) + 4 projections. 8 WAVES (512 thr)/block:
//   wave pair per weight, each wave half the i-tiles -> 2x resident waves
//   (R8 lesson: 13% occupancy, latency-bound). znl swizzle widened to
//   (i&15)<<4 -> conflict-free Phase-A writes AND Phase-B reads.
// ---------------------------------------------------------------------------
__global__ __launch_bounds__(512) void ln_qkvg_mfma(
    const float* __restrict__ z, const float* __restrict__ lnw, const float* __restrict__ lnb,
    const unsigned short* __restrict__ wT,
    const float* __restrict__ bq, const float* __restrict__ bk,
    const float* __restrict__ bv, const float* __restrict__ bg,
    unsigned short* __restrict__ q_ws, unsigned short* __restrict__ k_ws,
    unsigned short* __restrict__ v_ws, unsigned short* __restrict__ g_ws)
{
  __shared__ unsigned short znl[128 * DZc];   // 32 KB bf16 [i][c], XOR-swizzled

  const int t = threadIdx.x;
  const int pos0 = blockIdx.x * 128;
  const int n = pos0 >> 8;        // constant per block
  const int w8 = t >> 6;          // wave 0..7
  const int w  = w8 >> 1;         // weight index (0=q,1=k,2=v,3=g)
  const int ihalf = w8 & 1;       // which 4 i-tiles this wave owns
  const int l  = t & 63;
  const int lr = l & 15;
  const int lg = l >> 4;

  const unsigned short* wTw = wT + (size_t)w * (DZc * DHCc);
  const float* bptr = (w == 0) ? bq : (w == 1) ? bk : (w == 2) ? bv : bg;
  const float qscale = 0.17677669529663687f;

  // v-wave bias (per jc = jt*16+lr, lr baked in)
  float biasv[8];
  #pragma unroll
  for (int jt = 0; jt < 8; ++jt) biasv[jt] = bptr[jt * 16 + lr];

  // ---- Phase A: z in regs (4 pos x 8 ch/lane), 16-lane shfl stats, LN ----
  {
    const int pq = t >> 4;          // 0..31 pos-quad
    const int cg = t & 15;          // 0..15 channel group (8 ch each)
    const int gp = pos0 + pq * 4;
    const int cbase = cg * 8;

    float4 zr[8];
    #pragma unroll
    for (int cc = 0; cc < 8; ++cc)
      zr[cc] = *reinterpret_cast<const float4*>(&z[(size_t)(cbase + cc) * NPOSc + gp]);

    float s[4] = {0.f, 0.f, 0.f, 0.f}, s2[4] = {0.f, 0.f, 0.f, 0.f};
    #pragma unroll
    for (int cc = 0; cc < 8; ++cc) {
      s[0] += zr[cc].x; s2[0] += zr[cc].x * zr[cc].x;
      s[1] += zr[cc].y; s2[1] += zr[cc].y * zr[cc].y;
      s[2] += zr[cc].z; s2[2] += zr[cc].z * zr[cc].z;
      s[3] += zr[cc].w; s2[3] += zr[cc].w * zr[cc].w;
    }
    // reduce over the 16 lanes sharing pq: masks 1,2,4,8 stay in-group
    #pragma unroll
    for (int m = 1; m <= 8; m <<= 1) {
      #pragma unroll
      for (int e = 0; e < 4; ++e) {
        s[e]  += __shfl_xor(s[e],  m);
        s2[e] += __shfl_xor(s2[e], m);
      }
    }
    float mu[4], rs[4];
    #pragma unroll
    for (int e = 0; e < 4; ++e) {
      mu[e] = s[e] * (1.0f / DZc);
      const float var = s2[e] * (1.0f / DZc) - mu[e] * mu[e];
      rs[e] = rsqrtf(var + 1e-5f);
    }

    float lw[8], lb[8];
    #pragma unroll
    for (int q4 = 0; q4 < 2; ++q4) {
      const float4 a = *reinterpret_cast<const float4*>(&lnw[cbase + q4 * 4]);
      const float4 b = *reinterpret_cast<const float4*>(&lnb[cbase + q4 * 4]);
      lw[q4 * 4 + 0] = a.x; lw[q4 * 4 + 1] = a.y; lw[q4 * 4 + 2] = a.z; lw[q4 * 4 + 3] = a.w;
      lb[q4 * 4 + 0] = b.x; lb[q4 * 4 + 1] = b.y; lb[q4 * 4 + 2] = b.z; lb[q4 * 4 + 3] = b.w;
    }

    #pragma unroll
    for (int e = 0; e < 4; ++e) {
      const int i = pq * 4 + e;
      unsigned short pk[8];
      #pragma unroll
      for (int cc = 0; cc < 8; ++cc) {
        const float zc = (e == 0) ? zr[cc].x : (e == 1) ? zr[cc].y
                       : (e == 2) ? zr[cc].z : zr[cc].w;
        pk[cc] = f2bf((zc - mu[e]) * rs[e] * lw[cc] + lb[cc]);
      }
      int byte = i * 256 + cbase * 2;
      byte ^= ((i & 15) << 4);
      *reinterpret_cast<bf16x8*>(reinterpret_cast<char*>(znl) + byte) =
          *reinterpret_cast<const bf16x8*>(pk);
    }
  }
  __syncthreads();

  // ---- Phase B: GEMM, this wave: 4 i-tiles (ihalf), two j-half passes ----
  unsigned short* outp = (w == 0) ? q_ws : (w == 1) ? k_ws : (w == 2) ? v_ws : g_ws;
  const char* znlb = reinterpret_cast<const char*>(znl);

  #pragma unroll 1
  for (int jh = 0; jh < 2; ++jh) {
    bf16x8 bfrag[4][4];
    #pragma unroll
    for (int jt = 0; jt < 4; ++jt)
      #pragma unroll
      for (int kt = 0; kt < 4; ++kt)
        bfrag[jt][kt] = *reinterpret_cast<const bf16x8*>(
            &wTw[(size_t)(jh * 64 + jt * 16 + lr) * 128 + kt * 32 + lg * 8]);

    // bias for swapped waves: 4 consecutive jc at jc0 = jh*64+jt*16+lg*4
    float bias4[4][4];
    if (w != 2) {
      #pragma unroll
      for (int jt = 0; jt < 4; ++jt) {
        const float4 bb = *reinterpret_cast<const float4*>(
            &bptr[jh * 64 + jt * 16 + lg * 4]);
        bias4[jt][0] = bb.x; bias4[jt][1] = bb.y;
        bias4[jt][2] = bb.z; bias4[jt][3] = bb.w;
        if (w == 0) {
          #pragma unroll
          for (int r = 0; r < 4; ++r) bias4[jt][r] *= qscale;
        }
      }
    }

    #pragma unroll 1
    for (int itl = 0; itl < 4; ++itl) {
      const int it = ihalf * 4 + itl;
      bf16x8 afrag[4];
      #pragma unroll
      for (int kt = 0; kt < 4; ++kt) {
        const int i = it * 16 + lr;
        int byte = i * 256 + (kt * 64 + lg * 16);
        byte ^= ((i & 15) << 4);
        afrag[kt] = *reinterpret_cast<const bf16x8*>(znlb + byte);
      }
      f32x4 acc[4];
      #pragma unroll
      for (int jt = 0; jt < 4; ++jt) acc[jt] = (f32x4){0.f, 0.f, 0.f, 0.f};

      if (w == 2) {
        // ---- v: D[pos][jc], transposed store [n][h][ch][ii] (8B) ----
        #pragma unroll
        for (int kt = 0; kt < 4; ++kt)
          #pragma unroll
          for (int jt = 0; jt < 4; ++jt)
            acc[jt] = __builtin_amdgcn_mfma_f32_16x16x32_bf16(
                afrag[kt], bfrag[jt][kt], acc[jt], 0, 0, 0);
        const int ii0 = (pos0 & 255) + it * 16 + lg * 4;
        #pragma unroll
        for (int jt = 0; jt < 4; ++jt) {
          const int jc = jh * 64 + jt * 16 + lr;
          const float bb = biasv[jh * 4 + jt];
          const int h = jc >> 5, ch = jc & 31;
          unsigned short pk[4];
          #pragma unroll
          for (int r = 0; r < 4; ++r) pk[r] = f2bf(acc[jt][r] + bb);
          *reinterpret_cast<bf16x4*>(
              &outp[((size_t)(n * 4 + h) * 32 + ch) * 256 + ii0]) =
              *reinterpret_cast<const bf16x4*>(pk);
        }
      } else {
        // ---- q/k/g: SWAPPED -> D[jc][pos], packed 8B stores along ch ----
        #pragma unroll
        for (int kt = 0; kt < 4; ++kt)
          #pragma unroll
          for (int jt = 0; jt < 4; ++jt)
            acc[jt] = __builtin_amdgcn_mfma_f32_16x16x32_bf16(
                bfrag[jt][kt], afrag[kt], acc[jt], 0, 0, 0);
        const int pos = pos0 + it * 16 + lr;
        const int ii  = pos & 255;
        #pragma unroll
        for (int jt = 0; jt < 4; ++jt) {
          const int jc0 = jh * 64 + jt * 16 + lg * 4;
          unsigned short pk[4];
          #pragma unroll
          for (int r = 0; r < 4; ++r) {
            float vv = acc[jt][r] + bias4[jt][r];
            if (w == 3) vv = sigmoidf_(vv);
            pk[r] = f2bf(vv);
          }
          unsigned short* dst;
          if (w == 3) {
            dst = &outp[(size_t)pos * 128 + jc0];
          } else {
            const int h = jc0 >> 5, ch = jc0 & 31;
            dst = &outp[((size_t)(n * 4 + h) * 256 + ii) * 32 + ch];
          }
          *reinterpret_cast<bf16x4*>(dst) = *reinterpret_cast<const bf16x4*>(pk);
        }
      }
    }
  }
}

// ---------------------------------------------------------------------------
// K2: attention per (h,n). Swapped QK^T -> lane-local row-sum; max-free
//   softmax; P bounced via halved per-wave LDS (4 KB, two j-half rounds).
//   Gate prefetched at tile start; O*g written in place into g_ws [pos][128].
// ---------------------------------------------------------------------------
__global__ __launch_bounds__(256) void attn_mfma(
    const unsigned short* __restrict__ q, const unsigned short* __restrict__ k,
    const unsigned short* __restrict__ v, unsigned short* og_ws)
{
  __shared__ unsigned short kl[Lc * DCc];    // 16 KB [j][ch] swizzled
  __shared__ unsigned short vt[DCc * Lc];    // 16 KB [ch][j] swizzled
  __shared__ unsigned short pl[4][16 * 128]; // 4 x 4 KB per-wave P half, swizzled

  const int t = threadIdx.x;
  const int h = blockIdx.x, n = blockIdx.y;
  const int w = t >> 6, l = t & 63, lr = l & 15, lg = l >> 4;
  const size_t base = ((size_t)(n * Hc + h)) * (Lc * DCc);

  // ---- stage K: [j][ch] bf16, swizzle byte ^= (j&7)<<4 ----
  #pragma unroll
  for (int pass = 0; pass < 4; ++pass) {
    const int cid = pass * 256 + t;           // 1024 x 16B chunks
    const int j = cid >> 2, c = cid & 3;
    bf16x8 kk = *reinterpret_cast<const bf16x8*>(&k[base + (size_t)j * 32 + c * 8]);
    int byte = j * 64 + c * 16;
    byte ^= ((j & 7) << 4);
    *reinterpret_cast<bf16x8*>(reinterpret_cast<char*>(kl) + byte) = kk;
  }
  // ---- stage V (pre-transposed): straight copy, swizzle byte ^= (ch&7)<<4 ----
  #pragma unroll
  for (int pass = 0; pass < 4; ++pass) {
    const int cid = pass * 256 + t;           // 1024 x 16B chunks
    const int ch = cid >> 5, c = cid & 31;
    bf16x8 vv = *reinterpret_cast<const bf16x8*>(&v[base + (size_t)ch * 256 + c * 8]);
    int byte = ch * 512 + c * 16;
    byte ^= ((ch & 7) << 4);
    *reinterpret_cast<bf16x8*>(reinterpret_cast<char*>(vt) + byte) = vv;
  }
  __syncthreads();

  char* plb = reinterpret_cast<char*>(&pl[w][0]);
  const char* klb = reinterpret_cast<const char*>(kl);
  const char* vtb = reinterpret_cast<const char*>(vt);

  #pragma unroll 1
  for (int it = 0; it < 4; ++it) {
    const int ib = w * 64 + it * 16;          // this wave's 16 query rows

    // ---- prefetch gate values (latency hides under QK^T + softmax) ----
    unsigned short gpre[8];
    #pragma unroll
    for (int cht = 0; cht < 2; ++cht)
      #pragma unroll
      for (int r = 0; r < 4; ++r) {
        const int i = ib + lg * 4 + r;
        gpre[cht * 4 + r] =
            og_ws[((size_t)(n * Lc + i)) * 128 + h * 32 + cht * 16 + lr];
      }

    // Q B-frag: col i = lr, k(ch) = lg*8.. (direct from global, 1 KB/wave)
    bf16x8 qfrag = *reinterpret_cast<const bf16x8*>(
        &q[base + (size_t)(ib + lr) * 32 + lg * 8]);

    // ---- S^T = K · Q^T : 16 j-tiles ----
    f32x4 sacc[16];
    #pragma unroll
    for (int jt = 0; jt < 16; ++jt) sacc[jt] = (f32x4){0.f, 0.f, 0.f, 0.f};
    #pragma unroll
    for (int jt = 0; jt < 16; ++jt) {
      int byte = (jt * 16 + lr) * 64 + lg * 16;
      byte ^= ((lr & 7) << 4);
      bf16x8 kf = *reinterpret_cast<const bf16x8*>(klb + byte);
      sacc[jt] = __builtin_amdgcn_mfma_f32_16x16x32_bf16(kf, qfrag, sacc[jt], 0, 0, 0);
    }

    // ---- max-free softmax: exp in place, lane-local row sum ----
    float psum = 0.f;
    #pragma unroll
    for (int jt = 0; jt < 16; ++jt)
      #pragma unroll
      for (int r = 0; r < 4; ++r) {
        const float e = __expf(sacc[jt][r]);
        sacc[jt][r] = e;
        psum += e;
      }
    psum += __shfl_xor(psum, 16);
    psum += __shfl_xor(psum, 32);
    const float rl = 1.0f / psum;

    // ---- PV in two j-half rounds through the 4 KB per-wave buffer ----
    f32x4 oacc[2];
    oacc[0] = (f32x4){0.f, 0.f, 0.f, 0.f};
    oacc[1] = (f32x4){0.f, 0.f, 0.f, 0.f};
    #pragma unroll
    for (int jh2 = 0; jh2 < 2; ++jh2) {
      #pragma unroll
      for (int jt8 = 0; jt8 < 8; ++jt8) {
        const int jt = jh2 * 8 + jt8;
        unsigned w0 = (unsigned)f2bf(sacc[jt][0] * rl) |
                      ((unsigned)f2bf(sacc[jt][1] * rl) << 16);
        unsigned w1 = (unsigned)f2bf(sacc[jt][2] * rl) |
                      ((unsigned)f2bf(sacc[jt][3] * rl) << 16);
        int byte = lr * 256 + (jt8 * 16 + lg * 4) * 2;
        byte ^= ((lr & 7) << 4);
        uint2 pk; pk.x = w0; pk.y = w1;
        *reinterpret_cast<uint2*>(plb + byte) = pk;
      }
      asm volatile("s_waitcnt lgkmcnt(0)" ::: "memory");
      __builtin_amdgcn_sched_barrier(0);

      #pragma unroll
      for (int kt4 = 0; kt4 < 4; ++kt4) {
        int pbyte = lr * 256 + (kt4 * 64 + lg * 16);
        pbyte ^= ((lr & 7) << 4);
        bf16x8 pf = *reinterpret_cast<const bf16x8*>(plb + pbyte);
        const int kt = jh2 * 4 + kt4;
        #pragma unroll
        for (int cht = 0; cht < 2; ++cht) {
          const int ch = cht * 16 + lr;
          int vbyte = ch * 512 + (kt * 64 + lg * 16);
          vbyte ^= ((ch & 7) << 4);
          bf16x8 vf = *reinterpret_cast<const bf16x8*>(vtb + vbyte);
          oacc[cht] = __builtin_amdgcn_mfma_f32_16x16x32_bf16(pf, vf, oacc[cht], 0, 0, 0);
        }
      }
    }

    // ---- gate + store O in place over g (P already normalized) ----
    #pragma unroll
    for (int cht = 0; cht < 2; ++cht)
      #pragma unroll
      for (int r = 0; r < 4; ++r) {
        const int i = ib + lg * 4 + r;
        const size_t off = ((size_t)(n * Lc + i)) * 128 + h * 32 + cht * 16 + lr;
        og_ws[off] = f2bf(oacc[cht][r] * bf2f(gpre[cht * 4 + r]));
      }
  }
}

// ---------------------------------------------------------------------------
// K3: out^T = w2^T · (o·g)^T  -> out[c][pos] fp32, coalesced along pos.
// ---------------------------------------------------------------------------
__global__ __launch_bounds__(256) void outproj_mfma(
    const unsigned short* __restrict__ og_ws,
    const unsigned short* __restrict__ w2T, const float* __restrict__ b2,
    float* __restrict__ out)
{
  const int t = threadIdx.x;
  const int w = t >> 6, l = t & 63, lr = l & 15, lg = l >> 4;
  const int pos = blockIdx.x * 64 + w * 16 + lr;

  bf16x8 zb[4];
  #pragma unroll
  for (int kt = 0; kt < 4; ++kt)
    zb[kt] = *reinterpret_cast<const bf16x8*>(
        &og_ws[(size_t)pos * 128 + kt * 32 + lg * 8]);

  #pragma unroll
  for (int ct = 0; ct < 8; ++ct) {
    f32x4 acc = (f32x4){0.f, 0.f, 0.f, 0.f};
    #pragma unroll
    for (int kt = 0; kt < 4; ++kt) {
      bf16x8 af = *reinterpret_cast<const bf16x8*>(
          &w2T[(size_t)(ct * 16 + lr) * 128 + kt * 32 + lg * 8]);
      acc = __builtin_amdgcn_mfma_f32_16x16x32_bf16(af, zb[kt], acc, 0, 0, 0);
    }
    #pragma unroll
    for (int r = 0; r < 4; ++r) {
      const int c = ct * 16 + lg * 4 + r;
      out[(size_t)c * NPOSc + pos] = acc[r] + b2[c];
    }
  }
}

// ---------------------------------------------------------------------------
extern "C" void kernel_launch(void* const* d_in, const int* in_sizes, int n_in,
                              void* d_out, int out_size, void* d_ws, size_t ws_size,
                              hipStream_t stream) {
  const float* z   = (const float*)d_in[0];
  const float* lnw = (const float*)d_in[1];
  const float* lnb = (const float*)d_in[2];
  const float* wq  = (const float*)d_in[3];
  const float* bq  = (const float*)d_in[4];
  const float* wk  = (const float*)d_in[5];
  const float* bk  = (const float*)d_in[6];
  const float* wv  = (const float*)d_in[7];
  const float* bv  = (const float*)d_in[8];
  const float* wg  = (const float*)d_in[9];
  const float* bg  = (const float*)d_in[10];
  const float* w2  = (const float*)d_in[11];
  const float* b2  = (const float*)d_in[12];
  float* out = (float*)d_out;

  const size_t S = (size_t)NPOSc * DHCc;        // 8388608 elements
  unsigned short* ws = (unsigned short*)d_ws;
  unsigned short* q_ws = ws;                    // [n][h][i][ch]
  unsigned short* k_ws = ws + S;                // [n][h][j][ch]
  unsigned short* v_ws = ws + 2 * S;            // [n][h][ch][ii] (transposed)
  unsigned short* g_ws = ws + 3 * S;            // [pos][128]; becomes o*g in attn
  unsigned short* wT   = ws + 4 * S;            // 5 x 16384 bf16 weights

  prep_weights<<<5, 256, 0, stream>>>(wq, wk, wv, wg, w2, wT);
  ln_qkvg_mfma<<<NPOSc / 128, 512, 0, stream>>>(
      z, lnw, lnb, wT, bq, bk, bv, bg, q_ws, k_ws, v_ws, g_ws);
  attn_mfma<<<dim3(Hc, Lc), 256, 0, stream>>>(q_ws, k_ws, v_ws, g_ws);
  outproj_mfma<<<NPOSc / 64, 256, 0, stream>>>(
      g_ws, wT + 4 * (DZc * DHCc), b2, out);
}

// Round 10
// 110.203 us; speedup vs baseline: 1.0452x; 1.0452x over previous
//
#include <hip/hip_runtime.h>
#include <cstdint>
#include <cstddef>

#define DZc   128
#define Lc    256
#define Hc    4
#define DCc   32
#define DHCc  128
#define NPOSc (Lc * Lc)

typedef __attribute__((ext_vector_type(8))) short bf16x8;
typedef __attribute__((ext_vector_type(4))) short bf16x4;
typedef __attribute__((ext_vector_type(4))) float f32x4;

static __device__ __forceinline__ unsigned short f2bf(float f) {
  unsigned u = __float_as_uint(f);
  u += 0x7FFFu + ((u >> 16) & 1u);     // round-to-nearest-even
  return (unsigned short)(u >> 16);
}
static __device__ __forceinline__ float bf2f(unsigned short h) {
  return __uint_as_float(((unsigned)h) << 16);
}
static __device__ __forceinline__ float sigmoidf_(float x) {
  return 1.0f / (1.0f + __expf(-x));
}

// ---------------------------------------------------------------------------
// prep: weights fp32 [k][j] -> bf16 transposed [j][k]; q-scale folded into wq.
// slot 0..3 = wq,wk,wv,wg ; slot 4 = w2 (-> w2T[c][k]).
// ---------------------------------------------------------------------------
__global__ __launch_bounds__(256) void prep_weights(
    const float* __restrict__ wq, const float* __restrict__ wk,
    const float* __restrict__ wv, const float* __restrict__ wg,
    const float* __restrict__ w2, unsigned short* __restrict__ wT)
{
  const int b = blockIdx.x;  // 0..4
  const int t = threadIdx.x;
  const float* src = (b == 0) ? wq : (b == 1) ? wk : (b == 2) ? wv : (b == 3) ? wg : w2;
  unsigned short* dst = wT + (size_t)b * (DZc * DHCc);
  const float scale = (b == 0) ? 0.17677669529663687f : 1.0f;  // sqrt(1/32)
  for (int p = 0; p < 64; ++p) {
    const int idx = p * 256 + t;             // 16384 elements
    const int kk = idx >> 7, j = idx & 127;  // src[kk][j]
    dst[j * 128 + kk] = f2bf(src[idx] * scale);
  }
}

// ---------------------------------------------------------------------------
// K1 v7: LN (in-register stats) + 4 projections. 8 waves (512 thr)/block,
//   wave pair per weight SPLIT BY J-HALF (R9 lesson: i-split doubled bfrag
//   + afrag overhead per block; j-split keeps bfrag count = R8 while
//   doubling resident waves). Each wave: 16 bfrag, all 8 i-tiles.
// ---------------------------------------------------------------------------
__global__ __launch_bounds__(512) void ln_qkvg_mfma(
    const float* __restrict__ z, const float* __restrict__ lnw, const float* __restrict__ lnb,
    const unsigned short* __restrict__ wT,
    const float* __restrict__ bq, const float* __restrict__ bk,
    const float* __restrict__ bv, const float* __restrict__ bg,
    unsigned short* __restrict__ q_ws, unsigned short* __restrict__ k_ws,
    unsigned short* __restrict__ v_ws, unsigned short* __restrict__ g_ws)
{
  __shared__ unsigned short znl[128 * DZc];   // 32 KB bf16 [i][c], XOR-swizzled

  const int t = threadIdx.x;
  const int pos0 = blockIdx.x * 128;
  const int n = pos0 >> 8;        // constant per block
  const int w8 = t >> 6;          // wave 0..7
  const int w  = w8 >> 1;         // weight index (0=q,1=k,2=v,3=g)
  const int jh = w8 & 1;          // this wave's j-half (64 output ch)
  const int l  = t & 63;
  const int lr = l & 15;
  const int lg = l >> 4;

  const unsigned short* wTw = wT + (size_t)w * (DZc * DHCc);
  const float* bptr = (w == 0) ? bq : (w == 1) ? bk : (w == 2) ? bv : bg;
  const float qscale = 0.17677669529663687f;

  // ---- Phase A: z in regs (4 pos x 8 ch/lane), 16-lane shfl stats, LN ----
  {
    const int pq = t >> 4;          // 0..31 pos-quad
    const int cg = t & 15;          // 0..15 channel group (8 ch each)
    const int gp = pos0 + pq * 4;
    const int cbase = cg * 8;

    float4 zr[8];
    #pragma unroll
    for (int cc = 0; cc < 8; ++cc)
      zr[cc] = *reinterpret_cast<const float4*>(&z[(size_t)(cbase + cc) * NPOSc + gp]);

    float s[4] = {0.f, 0.f, 0.f, 0.f}, s2[4] = {0.f, 0.f, 0.f, 0.f};
    #pragma unroll
    for (int cc = 0; cc < 8; ++cc) {
      s[0] += zr[cc].x; s2[0] += zr[cc].x * zr[cc].x;
      s[1] += zr[cc].y; s2[1] += zr[cc].y * zr[cc].y;
      s[2] += zr[cc].z; s2[2] += zr[cc].z * zr[cc].z;
      s[3] += zr[cc].w; s2[3] += zr[cc].w * zr[cc].w;
    }
    // reduce over the 16 lanes sharing pq: masks 1,2,4,8 stay in-group
    #pragma unroll
    for (int m = 1; m <= 8; m <<= 1) {
      #pragma unroll
      for (int e = 0; e < 4; ++e) {
        s[e]  += __shfl_xor(s[e],  m);
        s2[e] += __shfl_xor(s2[e], m);
      }
    }
    float mu[4], rs[4];
    #pragma unroll
    for (int e = 0; e < 4; ++e) {
      mu[e] = s[e] * (1.0f / DZc);
      const float var = s2[e] * (1.0f / DZc) - mu[e] * mu[e];
      rs[e] = rsqrtf(var + 1e-5f);
    }

    float lw[8], lb[8];
    #pragma unroll
    for (int q4 = 0; q4 < 2; ++q4) {
      const float4 a = *reinterpret_cast<const float4*>(&lnw[cbase + q4 * 4]);
      const float4 b = *reinterpret_cast<const float4*>(&lnb[cbase + q4 * 4]);
      lw[q4 * 4 + 0] = a.x; lw[q4 * 4 + 1] = a.y; lw[q4 * 4 + 2] = a.z; lw[q4 * 4 + 3] = a.w;
      lb[q4 * 4 + 0] = b.x; lb[q4 * 4 + 1] = b.y; lb[q4 * 4 + 2] = b.z; lb[q4 * 4 + 3] = b.w;
    }

    #pragma unroll
    for (int e = 0; e < 4; ++e) {
      const int i = pq * 4 + e;
      unsigned short pk[8];
      #pragma unroll
      for (int cc = 0; cc < 8; ++cc) {
        const float zc = (e == 0) ? zr[cc].x : (e == 1) ? zr[cc].y
                       : (e == 2) ? zr[cc].z : zr[cc].w;
        pk[cc] = f2bf((zc - mu[e]) * rs[e] * lw[cc] + lb[cc]);
      }
      int byte = i * 256 + cbase * 2;
      byte ^= ((i & 15) << 4);
      *reinterpret_cast<bf16x8*>(reinterpret_cast<char*>(znl) + byte) =
          *reinterpret_cast<const bf16x8*>(pk);
    }
  }
  __syncthreads();

  // ---- Phase B: this wave = (weight w, j-half jh): 16 bfrag, 8 i-tiles ----
  unsigned short* outp = (w == 0) ? q_ws : (w == 1) ? k_ws : (w == 2) ? v_ws : g_ws;
  const char* znlb = reinterpret_cast<const char*>(znl);

  bf16x8 bfrag[4][4];
  #pragma unroll
  for (int jt = 0; jt < 4; ++jt)
    #pragma unroll
    for (int kt = 0; kt < 4; ++kt)
      bfrag[jt][kt] = *reinterpret_cast<const bf16x8*>(
          &wTw[(size_t)(jh * 64 + jt * 16 + lr) * 128 + kt * 32 + lg * 8]);

  // v-wave bias (per jc = jh*64+jt*16+lr)
  float biasv[4];
  #pragma unroll
  for (int jt = 0; jt < 4; ++jt) biasv[jt] = bptr[jh * 64 + jt * 16 + lr];

  // bias for swapped waves: 4 consecutive jc at jc0 = jh*64+jt*16+lg*4
  float bias4[4][4];
  if (w != 2) {
    #pragma unroll
    for (int jt = 0; jt < 4; ++jt) {
      const float4 bb = *reinterpret_cast<const float4*>(
          &bptr[jh * 64 + jt * 16 + lg * 4]);
      bias4[jt][0] = bb.x; bias4[jt][1] = bb.y;
      bias4[jt][2] = bb.z; bias4[jt][3] = bb.w;
      if (w == 0) {
        #pragma unroll
        for (int r = 0; r < 4; ++r) bias4[jt][r] *= qscale;
      }
    }
  }

  #pragma unroll 1
  for (int it = 0; it < 8; ++it) {
    bf16x8 afrag[4];
    #pragma unroll
    for (int kt = 0; kt < 4; ++kt) {
      const int i = it * 16 + lr;
      int byte = i * 256 + (kt * 64 + lg * 16);
      byte ^= ((i & 15) << 4);
      afrag[kt] = *reinterpret_cast<const bf16x8*>(znlb + byte);
    }
    f32x4 acc[4];
    #pragma unroll
    for (int jt = 0; jt < 4; ++jt) acc[jt] = (f32x4){0.f, 0.f, 0.f, 0.f};

    if (w == 2) {
      // ---- v: D[pos][jc], transposed store [n][h][ch][ii] (8B) ----
      #pragma unroll
      for (int kt = 0; kt < 4; ++kt)
        #pragma unroll
        for (int jt = 0; jt < 4; ++jt)
          acc[jt] = __builtin_amdgcn_mfma_f32_16x16x32_bf16(
              afrag[kt], bfrag[jt][kt], acc[jt], 0, 0, 0);
      const int ii0 = (pos0 & 255) + it * 16 + lg * 4;
      #pragma unroll
      for (int jt = 0; jt < 4; ++jt) {
        const int jc = jh * 64 + jt * 16 + lr;
        const float bb = biasv[jt];
        const int h = jc >> 5, ch = jc & 31;
        unsigned short pk[4];
        #pragma unroll
        for (int r = 0; r < 4; ++r) pk[r] = f2bf(acc[jt][r] + bb);
        *reinterpret_cast<bf16x4*>(
            &outp[((size_t)(n * 4 + h) * 32 + ch) * 256 + ii0]) =
            *reinterpret_cast<const bf16x4*>(pk);
      }
    } else {
      // ---- q/k/g: SWAPPED -> D[jc][pos], packed 8B stores along ch ----
      #pragma unroll
      for (int kt = 0; kt < 4; ++kt)
        #pragma unroll
        for (int jt = 0; jt < 4; ++jt)
          acc[jt] = __builtin_amdgcn_mfma_f32_16x16x32_bf16(
              bfrag[jt][kt], afrag[kt], acc[jt], 0, 0, 0);
      const int pos = pos0 + it * 16 + lr;
      const int ii  = pos & 255;
      #pragma unroll
      for (int jt = 0; jt < 4; ++jt) {
        const int jc0 = jh * 64 + jt * 16 + lg * 4;
        unsigned short pk[4];
        #pragma unroll
        for (int r = 0; r < 4; ++r) {
          float vv = acc[jt][r] + bias4[jt][r];
          if (w == 3) vv = sigmoidf_(vv);
          pk[r] = f2bf(vv);
        }
        unsigned short* dst;
        if (w == 3) {
          dst = &outp[(size_t)pos * 128 + jc0];
        } else {
          const int h = jc0 >> 5, ch = jc0 & 31;
          dst = &outp[((size_t)(n * 4 + h) * 256 + ii) * 32 + ch];
        }
        *reinterpret_cast<bf16x4*>(dst) = *reinterpret_cast<const bf16x4*>(pk);
      }
    }
  }
}

// ---------------------------------------------------------------------------
// K2: attention per (h,n). Swapped QK^T -> lane-local row-sum; max-free
//   softmax; P bounced via halved per-wave LDS (4 KB, two j-half rounds).
//   Gate prefetched at tile start; O*g written in place into g_ws [pos][128].
// ---------------------------------------------------------------------------
__global__ __launch_bounds__(256) void attn_mfma(
    const unsigned short* __restrict__ q, const unsigned short* __restrict__ k,
    const unsigned short* __restrict__ v, unsigned short* og_ws)
{
  __shared__ unsigned short kl[Lc * DCc];    // 16 KB [j][ch] swizzled
  __shared__ unsigned short vt[DCc * Lc];    // 16 KB [ch][j] swizzled
  __shared__ unsigned short pl[4][16 * 128]; // 4 x 4 KB per-wave P half, swizzled

  const int t = threadIdx.x;
  const int h = blockIdx.x, n = blockIdx.y;
  const int w = t >> 6, l = t & 63, lr = l & 15, lg = l >> 4;
  const size_t base = ((size_t)(n * Hc + h)) * (Lc * DCc);

  // ---- stage K: [j][ch] bf16, swizzle byte ^= (j&7)<<4 ----
  #pragma unroll
  for (int pass = 0; pass < 4; ++pass) {
    const int cid = pass * 256 + t;           // 1024 x 16B chunks
    const int j = cid >> 2, c = cid & 3;
    bf16x8 kk = *reinterpret_cast<const bf16x8*>(&k[base + (size_t)j * 32 + c * 8]);
    int byte = j * 64 + c * 16;
    byte ^= ((j & 7) << 4);
    *reinterpret_cast<bf16x8*>(reinterpret_cast<char*>(kl) + byte) = kk;
  }
  // ---- stage V (pre-transposed): straight copy, swizzle byte ^= (ch&7)<<4 ----
  #pragma unroll
  for (int pass = 0; pass < 4; ++pass) {
    const int cid = pass * 256 + t;           // 1024 x 16B chunks
    const int ch = cid >> 5, c = cid & 31;
    bf16x8 vv = *reinterpret_cast<const bf16x8*>(&v[base + (size_t)ch * 256 + c * 8]);
    int byte = ch * 512 + c * 16;
    byte ^= ((ch & 7) << 4);
    *reinterpret_cast<bf16x8*>(reinterpret_cast<char*>(vt) + byte) = vv;
  }
  __syncthreads();

  char* plb = reinterpret_cast<char*>(&pl[w][0]);
  const char* klb = reinterpret_cast<const char*>(kl);
  const char* vtb = reinterpret_cast<const char*>(vt);

  #pragma unroll 1
  for (int it = 0; it < 4; ++it) {
    const int ib = w * 64 + it * 16;          // this wave's 16 query rows

    // ---- prefetch gate values (latency hides under QK^T + softmax) ----
    unsigned short gpre[8];
    #pragma unroll
    for (int cht = 0; cht < 2; ++cht)
      #pragma unroll
      for (int r = 0; r < 4; ++r) {
        const int i = ib + lg * 4 + r;
        gpre[cht * 4 + r] =
            og_ws[((size_t)(n * Lc + i)) * 128 + h * 32 + cht * 16 + lr];
      }

    // Q B-frag: col i = lr, k(ch) = lg*8.. (direct from global, 1 KB/wave)
    bf16x8 qfrag = *reinterpret_cast<const bf16x8*>(
        &q[base + (size_t)(ib + lr) * 32 + lg * 8]);

    // ---- S^T = K · Q^T : 16 j-tiles ----
    f32x4 sacc[16];
    #pragma unroll
    for (int jt = 0; jt < 16; ++jt) sacc[jt] = (f32x4){0.f, 0.f, 0.f, 0.f};
    #pragma unroll
    for (int jt = 0; jt < 16; ++jt) {
      int byte = (jt * 16 + lr) * 64 + lg * 16;
      byte ^= ((lr & 7) << 4);
      bf16x8 kf = *reinterpret_cast<const bf16x8*>(klb + byte);
      sacc[jt] = __builtin_amdgcn_mfma_f32_16x16x32_bf16(kf, qfrag, sacc[jt], 0, 0, 0);
    }

    // ---- max-free softmax: exp in place, lane-local row sum ----
    float psum = 0.f;
    #pragma unroll
    for (int jt = 0; jt < 16; ++jt)
      #pragma unroll
      for (int r = 0; r < 4; ++r) {
        const float e = __expf(sacc[jt][r]);
        sacc[jt][r] = e;
        psum += e;
      }
    psum += __shfl_xor(psum, 16);
    psum += __shfl_xor(psum, 32);
    const float rl = 1.0f / psum;

    // ---- PV in two j-half rounds through the 4 KB per-wave buffer ----
    f32x4 oacc[2];
    oacc[0] = (f32x4){0.f, 0.f, 0.f, 0.f};
    oacc[1] = (f32x4){0.f, 0.f, 0.f, 0.f};
    #pragma unroll
    for (int jh2 = 0; jh2 < 2; ++jh2) {
      #pragma unroll
      for (int jt8 = 0; jt8 < 8; ++jt8) {
        const int jt = jh2 * 8 + jt8;
        unsigned w0 = (unsigned)f2bf(sacc[jt][0] * rl) |
                      ((unsigned)f2bf(sacc[jt][1] * rl) << 16);
        unsigned w1 = (unsigned)f2bf(sacc[jt][2] * rl) |
                      ((unsigned)f2bf(sacc[jt][3] * rl) << 16);
        int byte = lr * 256 + (jt8 * 16 + lg * 4) * 2;
        byte ^= ((lr & 7) << 4);
        uint2 pk; pk.x = w0; pk.y = w1;
        *reinterpret_cast<uint2*>(plb + byte) = pk;
      }
      asm volatile("s_waitcnt lgkmcnt(0)" ::: "memory");
      __builtin_amdgcn_sched_barrier(0);

      #pragma unroll
      for (int kt4 = 0; kt4 < 4; ++kt4) {
        int pbyte = lr * 256 + (kt4 * 64 + lg * 16);
        pbyte ^= ((lr & 7) << 4);
        bf16x8 pf = *reinterpret_cast<const bf16x8*>(plb + pbyte);
        const int kt = jh2 * 4 + kt4;
        #pragma unroll
        for (int cht = 0; cht < 2; ++cht) {
          const int ch = cht * 16 + lr;
          int vbyte = ch * 512 + (kt * 64 + lg * 16);
          vbyte ^= ((ch & 7) << 4);
          bf16x8 vf = *reinterpret_cast<const bf16x8*>(vtb + vbyte);
          oacc[cht] = __builtin_amdgcn_mfma_f32_16x16x32_bf16(pf, vf, oacc[cht], 0, 0, 0);
        }
      }
    }

    // ---- gate + store O in place over g (P already normalized) ----
    #pragma unroll
    for (int cht = 0; cht < 2; ++cht)
      #pragma unroll
      for (int r = 0; r < 4; ++r) {
        const int i = ib + lg * 4 + r;
        const size_t off = ((size_t)(n * Lc + i)) * 128 + h * 32 + cht * 16 + lr;
        og_ws[off] = f2bf(oacc[cht][r] * bf2f(gpre[cht * 4 + r]));
      }
  }
}

// ---------------------------------------------------------------------------
// K3: out^T = w2^T · (o·g)^T  -> out[c][pos] fp32, coalesced along pos.
// ---------------------------------------------------------------------------
__global__ __launch_bounds__(256) void outproj_mfma(
    const unsigned short* __restrict__ og_ws,
    const unsigned short* __restrict__ w2T, const float* __restrict__ b2,
    float* __restrict__ out)
{
  const int t = threadIdx.x;
  const int w = t >> 6, l = t & 63, lr = l & 15, lg = l >> 4;
  const int pos = blockIdx.x * 64 + w * 16 + lr;

  bf16x8 zb[4];
  #pragma unroll
  for (int kt = 0; kt < 4; ++kt)
    zb[kt] = *reinterpret_cast<const bf16x8*>(
        &og_ws[(size_t)pos * 128 + kt * 32 + lg * 8]);

  #pragma unroll
  for (int ct = 0; ct < 8; ++ct) {
    f32x4 acc = (f32x4){0.f, 0.f, 0.f, 0.f};
    #pragma unroll
    for (int kt = 0; kt < 4; ++kt) {
      bf16x8 af = *reinterpret_cast<const bf16x8*>(
          &w2T[(size_t)(ct * 16 + lr) * 128 + kt * 32 + lg * 8]);
      acc = __builtin_amdgcn_mfma_f32_16x16x32_bf16(af, zb[kt], acc, 0, 0, 0);
    }
    #pragma unroll
    for (int r = 0; r < 4; ++r) {
      const int c = ct * 16 + lg * 4 + r;
      out[(size_t)c * NPOSc + pos] = acc[r] + b2[c];
    }
  }
}

// ---------------------------------------------------------------------------
extern "C" void kernel_launch(void* const* d_in, const int* in_sizes, int n_in,
                              void* d_out, int out_size, void* d_ws, size_t ws_size,
                              hipStream_t stream) {
  const float* z   = (const float*)d_in[0];
  const float* lnw = (const float*)d_in[1];
  const float* lnb = (const float*)d_in[2];
  const float* wq  = (const float*)d_in[3];
  const float* bq  = (const float*)d_in[4];
  const float* wk  = (const float*)d_in[5];
  const float* bk  = (const float*)d_in[6];
  const float* wv  = (const float*)d_in[7];
  const float* bv  = (const float*)d_in[8];
  const float* wg  = (const float*)d_in[9];
  const float* bg  = (const float*)d_in[10];
  const float* w2  = (const float*)d_in[11];
  const float* b2  = (const float*)d_in[12];
  float* out = (float*)d_out;

  const size_t S = (size_t)NPOSc * DHCc;        // 8388608 elements
  unsigned short* ws = (unsigned short*)d_ws;
  unsigned short* q_ws = ws;                    // [n][h][i][ch]
  unsigned short* k_ws = ws + S;                // [n][h][j][ch]
  unsigned short* v_ws = ws + 2 * S;            // [n][h][ch][ii] (transposed)
  unsigned short* g_ws = ws + 3 * S;            // [pos][128]; becomes o*g in attn
  unsigned short* wT   = ws + 4 * S;            // 5 x 16384 bf16 weights

  prep_weights<<<5, 256, 0, stream>>>(wq, wk, wv, wg, w2, wT);
  ln_qkvg_mfma<<<NPOSc / 128, 512, 0, stream>>>(
      z, lnw, lnb, wT, bq, bk, bv, bg, q_ws, k_ws, v_ws, g_ws);
  attn_mfma<<<dim3(Hc, Lc), 256, 0, stream>>>(q_ws, k_ws, v_ws, g_ws);
  outproj_mfma<<<NPOSc / 64, 256, 0, stream>>>(
      g_ws, wT + 4 * (DZc * DHCc), b2, out);
}

// Round 11
// 89.759 us; speedup vs baseline: 1.2833x; 1.2278x over previous
//
#include <hip/hip_runtime.h>
#include <cstdint>
#include <cstddef>

#define DZc   128
#define Lc    256
#define Hc    4
#define DCc   32
#define DHCc  128
#define NPOSc (Lc * Lc)

typedef __attribute__((ext_vector_type(8))) short bf16x8;
typedef __attribute__((ext_vector_type(4))) short bf16x4;
typedef __attribute__((ext_vector_type(4))) float f32x4;

static __device__ __forceinline__ unsigned short f2bf(float f) {
  unsigned u = __float_as_uint(f);
  u += 0x7FFFu + ((u >> 16) & 1u);     // round-to-nearest-even
  return (unsigned short)(u >> 16);
}
static __device__ __forceinline__ float bf2f(unsigned short h) {
  return __uint_as_float(((unsigned)h) << 16);
}
static __device__ __forceinline__ float sigmoidf_(float x) {
  return 1.0f / (1.0f + __expf(-x));
}
static __device__ __forceinline__ unsigned packbf(float a, float b) {
  return (unsigned)f2bf(a) | ((unsigned)f2bf(b) << 16);
}

// ---------------------------------------------------------------------------
// prep: weights fp32 [k][j] -> bf16 transposed [j][k]; q-scale folded into wq.
// slot 0..3 = wq,wk,wv,wg ; slot 4 = w2 (-> w2T[c][k]).
// ---------------------------------------------------------------------------
__global__ __launch_bounds__(256) void prep_weights(
    const float* __restrict__ wq, const float* __restrict__ wk,
    const float* __restrict__ wv, const float* __restrict__ wg,
    const float* __restrict__ w2, unsigned short* __restrict__ wT)
{
  const int b = blockIdx.x;  // 0..4
  const int t = threadIdx.x;
  const float* src = (b == 0) ? wq : (b == 1) ? wk : (b == 2) ? wv : (b == 3) ? wg : w2;
  unsigned short* dst = wT + (size_t)b * (DZc * DHCc);
  const float scale = (b == 0) ? 0.17677669529663687f : 1.0f;  // sqrt(1/32)
  for (int p = 0; p < 64; ++p) {
    const int idx = p * 256 + t;             // 16384 elements
    const int kk = idx >> 7, j = idx & 127;  // src[kk][j]
    dst[j * 128 + kk] = f2bf(src[idx] * scale);
  }
}

// ---------------------------------------------------------------------------
// FUSED kernel: one block per n (256 blocks, 512 threads = 8 waves).
//   Phase A : LN -> zn bf16 in R1 (64KB LDS, swizzled (i&15)<<4)
//   Phase B : wave (h,ihalf):  q -> regs (attn B-frag layout via pack+shfl)
//                              g -> packed regs (lands in O's lane layout)
//             wave (chq,vih):  V -> R2 LDS [ch][ii] (64KB, swizzled)
//   Phase C : K -> R1 IN PLACE over zn, 4 row-chunks, 2 barriers each
//   Phase D : attention per (h,ihalf): QK^T (K from R1) -> max-free softmax
//             -> P quarter-bounce via R3 (2KB/wave) -> PV (V from R2)
//             -> og = o*g (gate from regs) -> global og[pos][128]
//   No q/k/v/g global round-trip at all.
// ---------------------------------------------------------------------------
__global__ __launch_bounds__(512, 2) void fused_ln_proj_attn(
    const float* __restrict__ z, const float* __restrict__ lnw, const float* __restrict__ lnb,
    const unsigned short* __restrict__ wT,
    const float* __restrict__ bq, const float* __restrict__ bk,
    const float* __restrict__ bv, const float* __restrict__ bg,
    unsigned short* __restrict__ og_ws)
{
  __shared__ unsigned short zkl[Lc * DZc];     // 64 KB: zn, later K [j][128ch]
  __shared__ unsigned short vtl[DHCc * Lc];    // 64 KB: V^T [ch][ii]
  __shared__ unsigned short pll[8][16 * 64];   // 16 KB: per-wave P quarter

  const int t  = threadIdx.x;
  const int n  = blockIdx.x;
  const int w8 = t >> 6;
  const int l  = t & 63;
  const int lr = l & 15;
  const int lg = l >> 4;
  const int h     = w8 & 3;      // head for q/g/attention
  const int ihalf = w8 >> 2;     // query-row half for q/g/attention

  char* zkb = reinterpret_cast<char*>(zkl);
  char* vtb = reinterpret_cast<char*>(vtl);
  char* plb = reinterpret_cast<char*>(&pll[w8][0]);

  // ---- Phase A: LN (in-register stats, 16-lane shfl tree), 2 passes ----
  #pragma unroll
  for (int p = 0; p < 2; ++p) {
    const int pq = t >> 4;          // 0..31 pos-quad
    const int cg = t & 15;          // 0..15 channel group (8 ch)
    const int gp = n * 256 + p * 128 + pq * 4;
    const int cbase = cg * 8;

    float4 zr[8];
    #pragma unroll
    for (int cc = 0; cc < 8; ++cc)
      zr[cc] = *reinterpret_cast<const float4*>(&z[(size_t)(cbase + cc) * NPOSc + gp]);

    float s[4] = {0.f, 0.f, 0.f, 0.f}, s2[4] = {0.f, 0.f, 0.f, 0.f};
    #pragma unroll
    for (int cc = 0; cc < 8; ++cc) {
      s[0] += zr[cc].x; s2[0] += zr[cc].x * zr[cc].x;
      s[1] += zr[cc].y; s2[1] += zr[cc].y * zr[cc].y;
      s[2] += zr[cc].z; s2[2] += zr[cc].z * zr[cc].z;
      s[3] += zr[cc].w; s2[3] += zr[cc].w * zr[cc].w;
    }
    #pragma unroll
    for (int m = 1; m <= 8; m <<= 1) {
      #pragma unroll
      for (int e = 0; e < 4; ++e) {
        s[e]  += __shfl_xor(s[e],  m);
        s2[e] += __shfl_xor(s2[e], m);
      }
    }
    float mu[4], rs[4];
    #pragma unroll
    for (int e = 0; e < 4; ++e) {
      mu[e] = s[e] * (1.0f / DZc);
      const float var = s2[e] * (1.0f / DZc) - mu[e] * mu[e];
      rs[e] = rsqrtf(var + 1e-5f);
    }
    float lw[8], lb[8];
    #pragma unroll
    for (int q4 = 0; q4 < 2; ++q4) {
      const float4 a = *reinterpret_cast<const float4*>(&lnw[cbase + q4 * 4]);
      const float4 b = *reinterpret_cast<const float4*>(&lnb[cbase + q4 * 4]);
      lw[q4 * 4 + 0] = a.x; lw[q4 * 4 + 1] = a.y; lw[q4 * 4 + 2] = a.z; lw[q4 * 4 + 3] = a.w;
      lb[q4 * 4 + 0] = b.x; lb[q4 * 4 + 1] = b.y; lb[q4 * 4 + 2] = b.z; lb[q4 * 4 + 3] = b.w;
    }
    #pragma unroll
    for (int e = 0; e < 4; ++e) {
      const int i = p * 128 + pq * 4 + e;
      unsigned short pk[8];
      #pragma unroll
      for (int cc = 0; cc < 8; ++cc) {
        const float zc = (e == 0) ? zr[cc].x : (e == 1) ? zr[cc].y
                       : (e == 2) ? zr[cc].z : zr[cc].w;
        pk[cc] = f2bf((zc - mu[e]) * rs[e] * lw[cc] + lb[cc]);
      }
      int byte = i * 256 + cbase * 2;
      byte ^= ((i & 15) << 4);
      *reinterpret_cast<bf16x8*>(zkb + byte) = *reinterpret_cast<const bf16x8*>(pk);
    }
  }
  __syncthreads();

  const unsigned short* wqT = wT;
  const unsigned short* wkT = wT + 1 * (DZc * DHCc);
  const unsigned short* wvT = wT + 2 * (DZc * DHCc);
  const unsigned short* wgT = wT + 3 * (DZc * DHCc);

  // ---- Phase B1: q -> qfrag[8] regs (attn B-frag layout) ----
  bf16x8 qfrag[8];
  {
    bf16x8 bfq[2][4];
    float4 qb4[2];
    #pragma unroll
    for (int jt = 0; jt < 2; ++jt) {
      #pragma unroll
      for (int kt = 0; kt < 4; ++kt)
        bfq[jt][kt] = *reinterpret_cast<const bf16x8*>(
            &wqT[(size_t)(h * 32 + jt * 16 + lr) * 128 + kt * 32 + lg * 8]);
      qb4[jt] = *reinterpret_cast<const float4*>(&bq[h * 32 + jt * 16 + lg * 4]);
      qb4[jt].x *= 0.17677669529663687f; qb4[jt].y *= 0.17677669529663687f;
      qb4[jt].z *= 0.17677669529663687f; qb4[jt].w *= 0.17677669529663687f;
    }
    #pragma unroll
    for (int it = 0; it < 8; ++it) {
      bf16x8 af[4];
      #pragma unroll
      for (int kt = 0; kt < 4; ++kt) {
        const int i = ihalf * 128 + it * 16 + lr;
        int byte = i * 256 + (kt * 64 + lg * 16);
        byte ^= ((i & 15) << 4);
        af[kt] = *reinterpret_cast<const bf16x8*>(zkb + byte);
      }
      f32x4 qa[2];
      qa[0] = (f32x4){0.f, 0.f, 0.f, 0.f};
      qa[1] = (f32x4){0.f, 0.f, 0.f, 0.f};
      #pragma unroll
      for (int kt = 0; kt < 4; ++kt)
        #pragma unroll
        for (int jt = 0; jt < 2; ++jt)
          qa[jt] = __builtin_amdgcn_mfma_f32_16x16x32_bf16(bfq[jt][kt], af[kt], qa[jt], 0, 0, 0);
      // srcw[jt][w]: ch = h*32 + jt*16 + lg*4 + 2w+{0,1}, pos = lr
      unsigned srcw0[2], srcw1[2];
      srcw0[0] = packbf(qa[0][0] + qb4[0].x, qa[0][1] + qb4[0].y);
      srcw0[1] = packbf(qa[0][2] + qb4[0].z, qa[0][3] + qb4[0].w);
      srcw1[0] = packbf(qa[1][0] + qb4[1].x, qa[1][1] + qb4[1].y);
      srcw1[1] = packbf(qa[1][2] + qb4[1].z, qa[1][3] + qb4[1].w);
      // shuffle to qfrag: lane wants row lr, ch octet lg*8 (quad 2lg, 2lg+1)
      unsigned qw[4];
      #pragma unroll
      for (int i4 = 0; i4 < 4; ++i4) {
        const int quad = lg * 2 + (i4 >> 1);
        const int srcl = (quad & 3) * 16 + lr;
        const unsigned a = (unsigned)__shfl((int)srcw0[i4 & 1], srcl);
        const unsigned b = (unsigned)__shfl((int)srcw1[i4 & 1], srcl);
        qw[i4] = (lg >= 2) ? b : a;   // jt_src = quad>>2 == (lg>=2)
      }
      uint4 qv; qv.x = qw[0]; qv.y = qw[1]; qv.z = qw[2]; qv.w = qw[3];
      qfrag[it] = *reinterpret_cast<const bf16x8*>(&qv);
    }
  }

  // ---- Phase B2: g -> gpk[8][2][2] packed regs (O lane layout) ----
  unsigned gpk[8][2][2];
  {
    bf16x8 bfg[2][4];
    float gb[2];
    #pragma unroll
    for (int jt = 0; jt < 2; ++jt) {
      #pragma unroll
      for (int kt = 0; kt < 4; ++kt)
        bfg[jt][kt] = *reinterpret_cast<const bf16x8*>(
            &wgT[(size_t)(h * 32 + jt * 16 + lr) * 128 + kt * 32 + lg * 8]);
      gb[jt] = bg[h * 32 + jt * 16 + lr];
    }
    #pragma unroll
    for (int it = 0; it < 8; ++it) {
      bf16x8 af[4];
      #pragma unroll
      for (int kt = 0; kt < 4; ++kt) {
        const int i = ihalf * 128 + it * 16 + lr;
        int byte = i * 256 + (kt * 64 + lg * 16);
        byte ^= ((i & 15) << 4);
        af[kt] = *reinterpret_cast<const bf16x8*>(zkb + byte);
      }
      f32x4 ga[2];
      ga[0] = (f32x4){0.f, 0.f, 0.f, 0.f};
      ga[1] = (f32x4){0.f, 0.f, 0.f, 0.f};
      #pragma unroll
      for (int kt = 0; kt < 4; ++kt)
        #pragma unroll
        for (int jt = 0; jt < 2; ++jt)
          ga[jt] = __builtin_amdgcn_mfma_f32_16x16x32_bf16(af[kt], bfg[jt][kt], ga[jt], 0, 0, 0);
      #pragma unroll
      for (int jt = 0; jt < 2; ++jt) {
        gpk[it][jt][0] = packbf(sigmoidf_(ga[jt][0] + gb[jt]), sigmoidf_(ga[jt][1] + gb[jt]));
        gpk[it][jt][1] = packbf(sigmoidf_(ga[jt][2] + gb[jt]), sigmoidf_(ga[jt][3] + gb[jt]));
      }
    }
  }

  // ---- Phase B3: V -> R2 LDS [ch][ii] (wave = (chq, vih)) ----
  {
    const int chq = w8 & 3, vih = w8 >> 2;
    bf16x8 bfv[2][4];
    float vb[2];
    #pragma unroll
    for (int jt = 0; jt < 2; ++jt) {
      #pragma unroll
      for (int kt = 0; kt < 4; ++kt)
        bfv[jt][kt] = *reinterpret_cast<const bf16x8*>(
            &wvT[(size_t)(chq * 32 + jt * 16 + lr) * 128 + kt * 32 + lg * 8]);
      vb[jt] = bv[chq * 32 + jt * 16 + lr];
    }
    #pragma unroll 1
    for (int it = 0; it < 8; ++it) {
      bf16x8 af[4];
      #pragma unroll
      for (int kt = 0; kt < 4; ++kt) {
        const int i = vih * 128 + it * 16 + lr;
        int byte = i * 256 + (kt * 64 + lg * 16);
        byte ^= ((i & 15) << 4);
        af[kt] = *reinterpret_cast<const bf16x8*>(zkb + byte);
      }
      f32x4 va[2];
      va[0] = (f32x4){0.f, 0.f, 0.f, 0.f};
      va[1] = (f32x4){0.f, 0.f, 0.f, 0.f};
      #pragma unroll
      for (int kt = 0; kt < 4; ++kt)
        #pragma unroll
        for (int jt = 0; jt < 2; ++jt)
          va[jt] = __builtin_amdgcn_mfma_f32_16x16x32_bf16(af[kt], bfv[jt][kt], va[jt], 0, 0, 0);
      const int ii0 = vih * 128 + it * 16 + lg * 4;
      #pragma unroll
      for (int jt = 0; jt < 2; ++jt) {
        const int ch = chq * 32 + jt * 16 + lr;
        unsigned short pk[4];
        #pragma unroll
        for (int r = 0; r < 4; ++r) pk[r] = f2bf(va[jt][r] + vb[jt]);
        int byte = ch * 512 + ii0 * 2;
        byte ^= ((ch & 7) << 4);
        *reinterpret_cast<bf16x4*>(vtb + byte) = *reinterpret_cast<const bf16x4*>(pk);
      }
    }
  }

  // ---- Phase C: K over R1 in place, 4 chunks of 64 rows (wave = jt w8) ----
  {
    bf16x8 bfk[4];
    #pragma unroll
    for (int kt = 0; kt < 4; ++kt)
      bfk[kt] = *reinterpret_cast<const bf16x8*>(
          &wkT[(size_t)(w8 * 16 + lr) * 128 + kt * 32 + lg * 8]);
    const float4 kb4 = *reinterpret_cast<const float4*>(&bk[w8 * 16 + lg * 4]);
    const float kb[4] = {kb4.x, kb4.y, kb4.z, kb4.w};

    #pragma unroll 1
    for (int c = 0; c < 4; ++c) {
      bf16x8 afr[4][4];
      #pragma unroll
      for (int itc = 0; itc < 4; ++itc)
        #pragma unroll
        for (int kt = 0; kt < 4; ++kt) {
          const int i = c * 64 + itc * 16 + lr;
          int byte = i * 256 + (kt * 64 + lg * 16);
          byte ^= ((i & 15) << 4);
          afr[itc][kt] = *reinterpret_cast<const bf16x8*>(zkb + byte);
        }
      __syncthreads();   // all reads of these rows done (all waves)
      #pragma unroll
      for (int itc = 0; itc < 4; ++itc) {
        f32x4 ka = (f32x4){0.f, 0.f, 0.f, 0.f};
        #pragma unroll
        for (int kt = 0; kt < 4; ++kt)
          ka = __builtin_amdgcn_mfma_f32_16x16x32_bf16(bfk[kt], afr[itc][kt], ka, 0, 0, 0);
        const int j = c * 64 + itc * 16 + lr;
        unsigned short pk[4];
        #pragma unroll
        for (int r = 0; r < 4; ++r) pk[r] = f2bf(ka[r] + kb[r]);
        int byte = j * 256 + (w8 * 16 + lg * 4) * 2;
        byte ^= ((j & 15) << 4);
        *reinterpret_cast<bf16x4*>(zkb + byte) = *reinterpret_cast<const bf16x4*>(pk);
      }
      __syncthreads();   // K rows visible before next chunk / attention
    }
  }

  // ---- Phase D: attention per (h, ihalf); 8 i-tiles of 16 query rows ----
  #pragma unroll
  for (int it = 0; it < 8; ++it) {
    // ---- S^T = K · Q^T over all 256 keys ----
    f32x4 sacc[16];
    #pragma unroll
    for (int jt = 0; jt < 16; ++jt) sacc[jt] = (f32x4){0.f, 0.f, 0.f, 0.f};
    #pragma unroll
    for (int jt = 0; jt < 16; ++jt) {
      const int j = jt * 16 + lr;
      int byte = j * 256 + h * 64 + lg * 16;
      byte ^= ((j & 15) << 4);
      bf16x8 kf = *reinterpret_cast<const bf16x8*>(zkb + byte);
      sacc[jt] = __builtin_amdgcn_mfma_f32_16x16x32_bf16(kf, qfrag[it], sacc[jt], 0, 0, 0);
    }

    // ---- max-free softmax ----
    float psum = 0.f;
    #pragma unroll
    for (int jt = 0; jt < 16; ++jt)
      #pragma unroll
      for (int r = 0; r < 4; ++r) {
        const float e = __expf(sacc[jt][r]);
        sacc[jt][r] = e;
        psum += e;
      }
    psum += __shfl_xor(psum, 16);
    psum += __shfl_xor(psum, 32);
    const float rl = 1.0f / psum;

    // ---- PV in 4 quarter rounds (2KB/wave P buffer) ----
    f32x4 oacc[2];
    oacc[0] = (f32x4){0.f, 0.f, 0.f, 0.f};
    oacc[1] = (f32x4){0.f, 0.f, 0.f, 0.f};
    #pragma unroll
    for (int qr = 0; qr < 4; ++qr) {
      #pragma unroll
      for (int jj = 0; jj < 4; ++jj) {
        const int jt = qr * 4 + jj;
        uint2 pk;
        pk.x = packbf(sacc[jt][0] * rl, sacc[jt][1] * rl);
        pk.y = packbf(sacc[jt][2] * rl, sacc[jt][3] * rl);
        int byte = lr * 128 + (jj * 16 + lg * 4) * 2;
        byte ^= ((lr & 7) << 4);
        *reinterpret_cast<uint2*>(plb + byte) = pk;
      }
      asm volatile("s_waitcnt lgkmcnt(0)" ::: "memory");
      __builtin_amdgcn_sched_barrier(0);
      #pragma unroll
      for (int kq = 0; kq < 2; ++kq) {
        int pbyte = lr * 128 + (kq * 64 + lg * 16);
        pbyte ^= ((lr & 7) << 4);
        bf16x8 pf = *reinterpret_cast<const bf16x8*>(plb + pbyte);
        #pragma unroll
        for (int cht = 0; cht < 2; ++cht) {
          const int ch = h * 32 + cht * 16 + lr;
          int vbyte = ch * 512 + (qr * 128 + kq * 64 + lg * 16);
          vbyte ^= ((ch & 7) << 4);
          bf16x8 vf = *reinterpret_cast<const bf16x8*>(vtb + vbyte);
          oacc[cht] = __builtin_amdgcn_mfma_f32_16x16x32_bf16(pf, vf, oacc[cht], 0, 0, 0);
        }
      }
    }

    // ---- gate (from regs) + store og [pos][128] ----
    #pragma unroll
    for (int cht = 0; cht < 2; ++cht)
      #pragma unroll
      for (int r = 0; r < 4; ++r) {
        const int i = ihalf * 128 + it * 16 + lg * 4 + r;
        const float gv = bf2f((unsigned short)((gpk[it][cht][r >> 1] >> ((r & 1) * 16)) & 0xffff));
        const size_t off = ((size_t)(n * Lc + i)) * 128 + h * 32 + cht * 16 + lr;
        og_ws[off] = f2bf(oacc[cht][r] * gv);
      }
  }
}

// ---------------------------------------------------------------------------
// K3: out^T = w2^T · (o·g)^T  -> out[c][pos] fp32, coalesced along pos.
// ---------------------------------------------------------------------------
__global__ __launch_bounds__(256) void outproj_mfma(
    const unsigned short* __restrict__ og_ws,
    const unsigned short* __restrict__ w2T, const float* __restrict__ b2,
    float* __restrict__ out)
{
  const int t = threadIdx.x;
  const int w = t >> 6, l = t & 63, lr = l & 15, lg = l >> 4;
  const int pos = blockIdx.x * 64 + w * 16 + lr;

  bf16x8 zb[4];
  #pragma unroll
  for (int kt = 0; kt < 4; ++kt)
    zb[kt] = *reinterpret_cast<const bf16x8*>(
        &og_ws[(size_t)pos * 128 + kt * 32 + lg * 8]);

  #pragma unroll
  for (int ct = 0; ct < 8; ++ct) {
    f32x4 acc = (f32x4){0.f, 0.f, 0.f, 0.f};
    #pragma unroll
    for (int kt = 0; kt < 4; ++kt) {
      bf16x8 af = *reinterpret_cast<const bf16x8*>(
          &w2T[(size_t)(ct * 16 + lr) * 128 + kt * 32 + lg * 8]);
      acc = __builtin_amdgcn_mfma_f32_16x16x32_bf16(af, zb[kt], acc, 0, 0, 0);
    }
    #pragma unroll
    for (int r = 0; r < 4; ++r) {
      const int c = ct * 16 + lg * 4 + r;
      out[(size_t)c * NPOSc + pos] = acc[r] + b2[c];
    }
  }
}

// ---------------------------------------------------------------------------
extern "C" void kernel_launch(void* const* d_in, const int* in_sizes, int n_in,
                              void* d_out, int out_size, void* d_ws, size_t ws_size,
                              hipStream_t stream) {
  const float* z   = (const float*)d_in[0];
  const float* lnw = (const float*)d_in[1];
  const float* lnb = (const float*)d_in[2];
  const float* wq  = (const float*)d_in[3];
  const float* bq  = (const float*)d_in[4];
  const float* wk  = (const float*)d_in[5];
  const float* bk  = (const float*)d_in[6];
  const float* wv  = (const float*)d_in[7];
  const float* bv  = (const float*)d_in[8];
  const float* wg  = (const float*)d_in[9];
  const float* bg  = (const float*)d_in[10];
  const float* w2  = (const float*)d_in[11];
  const float* b2  = (const float*)d_in[12];
  float* out = (float*)d_out;

  const size_t S = (size_t)NPOSc * DHCc;        // 8388608 elements
  unsigned short* ws = (unsigned short*)d_ws;
  unsigned short* og_ws = ws;                   // [pos][128] gated attn output
  unsigned short* wT    = ws + S;               // 5 x 16384 bf16 weights

  prep_weights<<<5, 256, 0, stream>>>(wq, wk, wv, wg, w2, wT);
  fused_ln_proj_attn<<<Lc, 512, 0, stream>>>(
      z, lnw, lnb, wT, bq, bk, bv, bg, og_ws);
  outproj_mfma<<<NPOSc / 64, 256, 0, stream>>>(
      og_ws, wT + 4 * (DZc * DHCc), b2, out);
}

// Round 12
// 80.071 us; speedup vs baseline: 1.4386x; 1.1210x over previous
//
#include <hip/hip_runtime.h>
#include <cstdint>
#include <cstddef>

#define DZc   128
#define Lc    256
#define Hc    4
#define DCc   32
#define DHCc  128
#define NPOSc (Lc * Lc)

typedef __attribute__((ext_vector_type(8))) short bf16x8;
typedef __attribute__((ext_vector_type(4))) short bf16x4;
typedef __attribute__((ext_vector_type(4))) float f32x4;

static __device__ __forceinline__ unsigned short f2bf(float f) {
  unsigned u = __float_as_uint(f);
  u += 0x7FFFu + ((u >> 16) & 1u);     // round-to-nearest-even
  return (unsigned short)(u >> 16);
}
static __device__ __forceinline__ float bf2f(unsigned short h) {
  return __uint_as_float(((unsigned)h) << 16);
}
static __device__ __forceinline__ float sigmoidf_(float x) {
  return 1.0f / (1.0f + __expf(-x));
}
// HW packed f32->bf16 (RNE, bit-identical to f2bf): 1 instr instead of ~8.
static __device__ __forceinline__ unsigned cvtpk(float lo, float hi) {
  unsigned r;
  asm("v_cvt_pk_bf16_f32 %0, %1, %2" : "=v"(r) : "v"(lo), "v"(hi));
  return r;
}

// ---------------------------------------------------------------------------
// prep: weights fp32 [k][j] -> bf16 transposed [j][k]; q-scale folded into wq.
// slot 0..3 = wq,wk,wv,wg ; slot 4 = w2 (-> w2T[c][k]).
// ---------------------------------------------------------------------------
__global__ __launch_bounds__(256) void prep_weights(
    const float* __restrict__ wq, const float* __restrict__ wk,
    const float* __restrict__ wv, const float* __restrict__ wg,
    const float* __restrict__ w2, unsigned short* __restrict__ wT)
{
  const int b = blockIdx.x;  // 0..4
  const int t = threadIdx.x;
  const float* src = (b == 0) ? wq : (b == 1) ? wk : (b == 2) ? wv : (b == 3) ? wg : w2;
  unsigned short* dst = wT + (size_t)b * (DZc * DHCc);
  const float scale = (b == 0) ? 0.17677669529663687f : 1.0f;  // sqrt(1/32)
  for (int p = 0; p < 64; ++p) {
    const int idx = p * 256 + t;             // 16384 elements
    const int kk = idx >> 7, j = idx & 127;  // src[kk][j]
    dst[j * 128 + kk] = f2bf(src[idx] * scale);
  }
}

// ---------------------------------------------------------------------------
// FUSED kernel: one block per n (256 blocks, 512 threads = 8 waves).
//   R12 changes vs R11: all bulk f32->bf16 packs use v_cvt_pk_bf16_f32;
//   softmax normalization DEFERRED past PV (rl folded into gate store).
// ---------------------------------------------------------------------------
__global__ __launch_bounds__(512, 2) void fused_ln_proj_attn(
    const float* __restrict__ z, const float* __restrict__ lnw, const float* __restrict__ lnb,
    const unsigned short* __restrict__ wT,
    const float* __restrict__ bq, const float* __restrict__ bk,
    const float* __restrict__ bv, const float* __restrict__ bg,
    unsigned short* __restrict__ og_ws)
{
  __shared__ unsigned short zkl[Lc * DZc];     // 64 KB: zn, later K [j][128ch]
  __shared__ unsigned short vtl[DHCc * Lc];    // 64 KB: V^T [ch][ii]
  __shared__ unsigned short pll[8][16 * 64];   // 16 KB: per-wave P quarter

  const int t  = threadIdx.x;
  const int n  = blockIdx.x;
  const int w8 = t >> 6;
  const int l  = t & 63;
  const int lr = l & 15;
  const int lg = l >> 4;
  const int h     = w8 & 3;      // head for q/g/attention
  const int ihalf = w8 >> 2;     // query-row half for q/g/attention

  char* zkb = reinterpret_cast<char*>(zkl);
  char* vtb = reinterpret_cast<char*>(vtl);
  char* plb = reinterpret_cast<char*>(&pll[w8][0]);

  // ---- Phase A: LN (in-register stats, 16-lane shfl tree), 2 passes ----
  #pragma unroll
  for (int p = 0; p < 2; ++p) {
    const int pq = t >> 4;          // 0..31 pos-quad
    const int cg = t & 15;          // 0..15 channel group (8 ch)
    const int gp = n * 256 + p * 128 + pq * 4;
    const int cbase = cg * 8;

    float4 zr[8];
    #pragma unroll
    for (int cc = 0; cc < 8; ++cc)
      zr[cc] = *reinterpret_cast<const float4*>(&z[(size_t)(cbase + cc) * NPOSc + gp]);

    float s[4] = {0.f, 0.f, 0.f, 0.f}, s2[4] = {0.f, 0.f, 0.f, 0.f};
    #pragma unroll
    for (int cc = 0; cc < 8; ++cc) {
      s[0] += zr[cc].x; s2[0] += zr[cc].x * zr[cc].x;
      s[1] += zr[cc].y; s2[1] += zr[cc].y * zr[cc].y;
      s[2] += zr[cc].z; s2[2] += zr[cc].z * zr[cc].z;
      s[3] += zr[cc].w; s2[3] += zr[cc].w * zr[cc].w;
    }
    #pragma unroll
    for (int m = 1; m <= 8; m <<= 1) {
      #pragma unroll
      for (int e = 0; e < 4; ++e) {
        s[e]  += __shfl_xor(s[e],  m);
        s2[e] += __shfl_xor(s2[e], m);
      }
    }
    float mu[4], rs[4];
    #pragma unroll
    for (int e = 0; e < 4; ++e) {
      mu[e] = s[e] * (1.0f / DZc);
      const float var = s2[e] * (1.0f / DZc) - mu[e] * mu[e];
      rs[e] = rsqrtf(var + 1e-5f);
    }
    float lw[8], lb[8];
    #pragma unroll
    for (int q4 = 0; q4 < 2; ++q4) {
      const float4 a = *reinterpret_cast<const float4*>(&lnw[cbase + q4 * 4]);
      const float4 b = *reinterpret_cast<const float4*>(&lnb[cbase + q4 * 4]);
      lw[q4 * 4 + 0] = a.x; lw[q4 * 4 + 1] = a.y; lw[q4 * 4 + 2] = a.z; lw[q4 * 4 + 3] = a.w;
      lb[q4 * 4 + 0] = b.x; lb[q4 * 4 + 1] = b.y; lb[q4 * 4 + 2] = b.z; lb[q4 * 4 + 3] = b.w;
    }
    #pragma unroll
    for (int e = 0; e < 4; ++e) {
      const int i = p * 128 + pq * 4 + e;
      float zn[8];
      #pragma unroll
      for (int cc = 0; cc < 8; ++cc) {
        const float zc = (e == 0) ? zr[cc].x : (e == 1) ? zr[cc].y
                       : (e == 2) ? zr[cc].z : zr[cc].w;
        zn[cc] = (zc - mu[e]) * rs[e] * lw[cc] + lb[cc];
      }
      uint4 pw;
      pw.x = cvtpk(zn[0], zn[1]); pw.y = cvtpk(zn[2], zn[3]);
      pw.z = cvtpk(zn[4], zn[5]); pw.w = cvtpk(zn[6], zn[7]);
      int byte = i * 256 + cbase * 2;
      byte ^= ((i & 15) << 4);
      *reinterpret_cast<uint4*>(zkb + byte) = pw;
    }
  }
  __syncthreads();

  const unsigned short* wqT = wT;
  const unsigned short* wkT = wT + 1 * (DZc * DHCc);
  const unsigned short* wvT = wT + 2 * (DZc * DHCc);
  const unsigned short* wgT = wT + 3 * (DZc * DHCc);

  // ---- Phase B1: q -> qfrag[8] regs (attn B-frag layout) ----
  bf16x8 qfrag[8];
  {
    bf16x8 bfq[2][4];
    float4 qb4[2];
    #pragma unroll
    for (int jt = 0; jt < 2; ++jt) {
      #pragma unroll
      for (int kt = 0; kt < 4; ++kt)
        bfq[jt][kt] = *reinterpret_cast<const bf16x8*>(
            &wqT[(size_t)(h * 32 + jt * 16 + lr) * 128 + kt * 32 + lg * 8]);
      qb4[jt] = *reinterpret_cast<const float4*>(&bq[h * 32 + jt * 16 + lg * 4]);
      qb4[jt].x *= 0.17677669529663687f; qb4[jt].y *= 0.17677669529663687f;
      qb4[jt].z *= 0.17677669529663687f; qb4[jt].w *= 0.17677669529663687f;
    }
    #pragma unroll
    for (int it = 0; it < 8; ++it) {
      bf16x8 af[4];
      #pragma unroll
      for (int kt = 0; kt < 4; ++kt) {
        const int i = ihalf * 128 + it * 16 + lr;
        int byte = i * 256 + (kt * 64 + lg * 16);
        byte ^= ((i & 15) << 4);
        af[kt] = *reinterpret_cast<const bf16x8*>(zkb + byte);
      }
      f32x4 qa[2];
      qa[0] = (f32x4){0.f, 0.f, 0.f, 0.f};
      qa[1] = (f32x4){0.f, 0.f, 0.f, 0.f};
      #pragma unroll
      for (int kt = 0; kt < 4; ++kt)
        #pragma unroll
        for (int jt = 0; jt < 2; ++jt)
          qa[jt] = __builtin_amdgcn_mfma_f32_16x16x32_bf16(bfq[jt][kt], af[kt], qa[jt], 0, 0, 0);
      // srcw[jt][w]: ch = h*32 + jt*16 + lg*4 + 2w+{0,1}, pos = lr
      unsigned srcw0[2], srcw1[2];
      srcw0[0] = cvtpk(qa[0][0] + qb4[0].x, qa[0][1] + qb4[0].y);
      srcw0[1] = cvtpk(qa[0][2] + qb4[0].z, qa[0][3] + qb4[0].w);
      srcw1[0] = cvtpk(qa[1][0] + qb4[1].x, qa[1][1] + qb4[1].y);
      srcw1[1] = cvtpk(qa[1][2] + qb4[1].z, qa[1][3] + qb4[1].w);
      // shuffle to qfrag: lane wants row lr, ch octet lg*8 (quad 2lg, 2lg+1)
      unsigned qw[4];
      #pragma unroll
      for (int i4 = 0; i4 < 4; ++i4) {
        const int quad = lg * 2 + (i4 >> 1);
        const int srcl = (quad & 3) * 16 + lr;
        const unsigned a = (unsigned)__shfl((int)srcw0[i4 & 1], srcl);
        const unsigned b = (unsigned)__shfl((int)srcw1[i4 & 1], srcl);
        qw[i4] = (lg >= 2) ? b : a;   // jt_src = quad>>2 == (lg>=2)
      }
      uint4 qv; qv.x = qw[0]; qv.y = qw[1]; qv.z = qw[2]; qv.w = qw[3];
      qfrag[it] = *reinterpret_cast<const bf16x8*>(&qv);
    }
  }

  // ---- Phase B2: g -> gpk[8][2][2] packed regs (O lane layout) ----
  unsigned gpk[8][2][2];
  {
    bf16x8 bfg[2][4];
    float gb[2];
    #pragma unroll
    for (int jt = 0; jt < 2; ++jt) {
      #pragma unroll
      for (int kt = 0; kt < 4; ++kt)
        bfg[jt][kt] = *reinterpret_cast<const bf16x8*>(
            &wgT[(size_t)(h * 32 + jt * 16 + lr) * 128 + kt * 32 + lg * 8]);
      gb[jt] = bg[h * 32 + jt * 16 + lr];
    }
    #pragma unroll
    for (int it = 0; it < 8; ++it) {
      bf16x8 af[4];
      #pragma unroll
      for (int kt = 0; kt < 4; ++kt) {
        const int i = ihalf * 128 + it * 16 + lr;
        int byte = i * 256 + (kt * 64 + lg * 16);
        byte ^= ((i & 15) << 4);
        af[kt] = *reinterpret_cast<const bf16x8*>(zkb + byte);
      }
      f32x4 ga[2];
      ga[0] = (f32x4){0.f, 0.f, 0.f, 0.f};
      ga[1] = (f32x4){0.f, 0.f, 0.f, 0.f};
      #pragma unroll
      for (int kt = 0; kt < 4; ++kt)
        #pragma unroll
        for (int jt = 0; jt < 2; ++jt)
          ga[jt] = __builtin_amdgcn_mfma_f32_16x16x32_bf16(af[kt], bfg[jt][kt], ga[jt], 0, 0, 0);
      #pragma unroll
      for (int jt = 0; jt < 2; ++jt) {
        gpk[it][jt][0] = cvtpk(sigmoidf_(ga[jt][0] + gb[jt]), sigmoidf_(ga[jt][1] + gb[jt]));
        gpk[it][jt][1] = cvtpk(sigmoidf_(ga[jt][2] + gb[jt]), sigmoidf_(ga[jt][3] + gb[jt]));
      }
    }
  }

  // ---- Phase B3: V -> R2 LDS [ch][ii] (wave = (chq, vih)) ----
  {
    const int chq = w8 & 3, vih = w8 >> 2;
    bf16x8 bfv[2][4];
    float vb[2];
    #pragma unroll
    for (int jt = 0; jt < 2; ++jt) {
      #pragma unroll
      for (int kt = 0; kt < 4; ++kt)
        bfv[jt][kt] = *reinterpret_cast<const bf16x8*>(
            &wvT[(size_t)(chq * 32 + jt * 16 + lr) * 128 + kt * 32 + lg * 8]);
      vb[jt] = bv[chq * 32 + jt * 16 + lr];
    }
    #pragma unroll 1
    for (int it = 0; it < 8; ++it) {
      bf16x8 af[4];
      #pragma unroll
      for (int kt = 0; kt < 4; ++kt) {
        const int i = vih * 128 + it * 16 + lr;
        int byte = i * 256 + (kt * 64 + lg * 16);
        byte ^= ((i & 15) << 4);
        af[kt] = *reinterpret_cast<const bf16x8*>(zkb + byte);
      }
      f32x4 va[2];
      va[0] = (f32x4){0.f, 0.f, 0.f, 0.f};
      va[1] = (f32x4){0.f, 0.f, 0.f, 0.f};
      #pragma unroll
      for (int kt = 0; kt < 4; ++kt)
        #pragma unroll
        for (int jt = 0; jt < 2; ++jt)
          va[jt] = __builtin_amdgcn_mfma_f32_16x16x32_bf16(af[kt], bfv[jt][kt], va[jt], 0, 0, 0);
      const int ii0 = vih * 128 + it * 16 + lg * 4;
      #pragma unroll
      for (int jt = 0; jt < 2; ++jt) {
        const int ch = chq * 32 + jt * 16 + lr;
        uint2 pv;
        pv.x = cvtpk(va[jt][0] + vb[jt], va[jt][1] + vb[jt]);
        pv.y = cvtpk(va[jt][2] + vb[jt], va[jt][3] + vb[jt]);
        int byte = ch * 512 + ii0 * 2;
        byte ^= ((ch & 7) << 4);
        *reinterpret_cast<uint2*>(vtb + byte) = pv;
      }
    }
  }

  // ---- Phase C: K over R1 in place, 4 chunks of 64 rows (wave = jt w8) ----
  {
    bf16x8 bfk[4];
    #pragma unroll
    for (int kt = 0; kt < 4; ++kt)
      bfk[kt] = *reinterpret_cast<const bf16x8*>(
          &wkT[(size_t)(w8 * 16 + lr) * 128 + kt * 32 + lg * 8]);
    const float4 kb4 = *reinterpret_cast<const float4*>(&bk[w8 * 16 + lg * 4]);
    const float kb[4] = {kb4.x, kb4.y, kb4.z, kb4.w};

    #pragma unroll 1
    for (int c = 0; c < 4; ++c) {
      bf16x8 afr[4][4];
      #pragma unroll
      for (int itc = 0; itc < 4; ++itc)
        #pragma unroll
        for (int kt = 0; kt < 4; ++kt) {
          const int i = c * 64 + itc * 16 + lr;
          int byte = i * 256 + (kt * 64 + lg * 16);
          byte ^= ((i & 15) << 4);
          afr[itc][kt] = *reinterpret_cast<const bf16x8*>(zkb + byte);
        }
      __syncthreads();   // all reads of these rows done (all waves)
      #pragma unroll
      for (int itc = 0; itc < 4; ++itc) {
        f32x4 ka = (f32x4){0.f, 0.f, 0.f, 0.f};
        #pragma unroll
        for (int kt = 0; kt < 4; ++kt)
          ka = __builtin_amdgcn_mfma_f32_16x16x32_bf16(bfk[kt], afr[itc][kt], ka, 0, 0, 0);
        const int j = c * 64 + itc * 16 + lr;
        uint2 pkk;
        pkk.x = cvtpk(ka[0] + kb[0], ka[1] + kb[1]);
        pkk.y = cvtpk(ka[2] + kb[2], ka[3] + kb[3]);
        int byte = j * 256 + (w8 * 16 + lg * 4) * 2;
        byte ^= ((j & 15) << 4);
        *reinterpret_cast<uint2*>(zkb + byte) = pkk;
      }
      __syncthreads();   // K rows visible before next chunk / attention
    }
  }

  // ---- Phase D: attention per (h, ihalf); 8 i-tiles of 16 query rows ----
  #pragma unroll
  for (int it = 0; it < 8; ++it) {
    // ---- S^T = K · Q^T over all 256 keys ----
    f32x4 sacc[16];
    #pragma unroll
    for (int jt = 0; jt < 16; ++jt) sacc[jt] = (f32x4){0.f, 0.f, 0.f, 0.f};
    #pragma unroll
    for (int jt = 0; jt < 16; ++jt) {
      const int j = jt * 16 + lr;
      int byte = j * 256 + h * 64 + lg * 16;
      byte ^= ((j & 15) << 4);
      bf16x8 kf = *reinterpret_cast<const bf16x8*>(zkb + byte);
      sacc[jt] = __builtin_amdgcn_mfma_f32_16x16x32_bf16(kf, qfrag[it], sacc[jt], 0, 0, 0);
    }

    // ---- max-free softmax: exp in place; NORMALIZATION DEFERRED past PV ----
    float psum = 0.f;
    #pragma unroll
    for (int jt = 0; jt < 16; ++jt)
      #pragma unroll
      for (int r = 0; r < 4; ++r) {
        const float e = __expf(sacc[jt][r]);
        sacc[jt][r] = e;
        psum += e;
      }
    psum += __shfl_xor(psum, 16);
    psum += __shfl_xor(psum, 32);
    const float rl = 1.0f / psum;

    // ---- PV in 4 quarter rounds (2KB/wave P buffer), unnormalized P ----
    f32x4 oacc[2];
    oacc[0] = (f32x4){0.f, 0.f, 0.f, 0.f};
    oacc[1] = (f32x4){0.f, 0.f, 0.f, 0.f};
    #pragma unroll
    for (int qr = 0; qr < 4; ++qr) {
      #pragma unroll
      for (int jj = 0; jj < 4; ++jj) {
        const int jt = qr * 4 + jj;
        uint2 pk;
        pk.x = cvtpk(sacc[jt][0], sacc[jt][1]);
        pk.y = cvtpk(sacc[jt][2], sacc[jt][3]);
        int byte = lr * 128 + (jj * 16 + lg * 4) * 2;
        byte ^= ((lr & 7) << 4);
        *reinterpret_cast<uint2*>(plb + byte) = pk;
      }
      asm volatile("s_waitcnt lgkmcnt(0)" ::: "memory");
      __builtin_amdgcn_sched_barrier(0);
      #pragma unroll
      for (int kq = 0; kq < 2; ++kq) {
        int pbyte = lr * 128 + (kq * 64 + lg * 16);
        pbyte ^= ((lr & 7) << 4);
        bf16x8 pf = *reinterpret_cast<const bf16x8*>(plb + pbyte);
        #pragma unroll
        for (int cht = 0; cht < 2; ++cht) {
          const int ch = h * 32 + cht * 16 + lr;
          int vbyte = ch * 512 + (qr * 128 + kq * 64 + lg * 16);
          vbyte ^= ((ch & 7) << 4);
          bf16x8 vf = *reinterpret_cast<const bf16x8*>(vtb + vbyte);
          oacc[cht] = __builtin_amdgcn_mfma_f32_16x16x32_bf16(pf, vf, oacc[cht], 0, 0, 0);
        }
      }
    }

    // ---- gate (from regs) + deferred normalize + store og [pos][128] ----
    #pragma unroll
    for (int cht = 0; cht < 2; ++cht)
      #pragma unroll
      for (int r = 0; r < 4; ++r) {
        const int i = ihalf * 128 + it * 16 + lg * 4 + r;
        const float gv = bf2f((unsigned short)((gpk[it][cht][r >> 1] >> ((r & 1) * 16)) & 0xffff));
        const size_t off = ((size_t)(n * Lc + i)) * 128 + h * 32 + cht * 16 + lr;
        og_ws[off] = f2bf(oacc[cht][r] * rl * gv);
      }
  }
}

// ---------------------------------------------------------------------------
// K3: out^T = w2^T · (o·g)^T  -> out[c][pos] fp32, coalesced along pos.
// ---------------------------------------------------------------------------
__global__ __launch_bounds__(256) void outproj_mfma(
    const unsigned short* __restrict__ og_ws,
    const unsigned short* __restrict__ w2T, const float* __restrict__ b2,
    float* __restrict__ out)
{
  const int t = threadIdx.x;
  const int w = t >> 6, l = t & 63, lr = l & 15, lg = l >> 4;
  const int pos = blockIdx.x * 64 + w * 16 + lr;

  bf16x8 zb[4];
  #pragma unroll
  for (int kt = 0; kt < 4; ++kt)
    zb[kt] = *reinterpret_cast<const bf16x8*>(
        &og_ws[(size_t)pos * 128 + kt * 32 + lg * 8]);

  #pragma unroll
  for (int ct = 0; ct < 8; ++ct) {
    f32x4 acc = (f32x4){0.f, 0.f, 0.f, 0.f};
    #pragma unroll
    for (int kt = 0; kt < 4; ++kt) {
      bf16x8 af = *reinterpret_cast<const bf16x8*>(
          &w2T[(size_t)(ct * 16 + lr) * 128 + kt * 32 + lg * 8]);
      acc = __builtin_amdgcn_mfma_f32_16x16x32_bf16(af, zb[kt], acc, 0, 0, 0);
    }
    #pragma unroll
    for (int r = 0; r < 4; ++r) {
      const int c = ct * 16 + lg * 4 + r;
      out[(size_t)c * NPOSc + pos] = acc[r] + b2[c];
    }
  }
}

// ---------------------------------------------------------------------------
extern "C" void kernel_launch(void* const* d_in, const int* in_sizes, int n_in,
                              void* d_out, int out_size, void* d_ws, size_t ws_size,
                              hipStream_t stream) {
  const float* z   = (const float*)d_in[0];
  const float* lnw = (const float*)d_in[1];
  const float* lnb = (const float*)d_in[2];
  const float* wq  = (const float*)d_in[3];
  const float* bq  = (const float*)d_in[4];
  const float* wk  = (const float*)d_in[5];
  const float* bk  = (const float*)d_in[6];
  const float* wv  = (const float*)d_in[7];
  const float* bv  = (const float*)d_in[8];
  const float* wg  = (const float*)d_in[9];
  const float* bg  = (const float*)d_in[10];
  const float* w2  = (const float*)d_in[11];
  const float* b2  = (const float*)d_in[12];
  float* out = (float*)d_out;

  const size_t S = (size_t)NPOSc * DHCc;        // 8388608 elements
  unsigned short* ws = (unsigned short*)d_ws;
  unsigned short* og_ws = ws;                   // [pos][128] gated attn output
  unsigned short* wT    = ws + S;               // 5 x 16384 bf16 weights

  prep_weights<<<5, 256, 0, stream>>>(wq, wk, wv, wg, w2, wT);
  fused_ln_proj_attn<<<Lc, 512, 0, stream>>>(
      z, lnw, lnb, wT, bq, bk, bv, bg, og_ws);
  outproj_mfma<<<NPOSc / 64, 256, 0, stream>>>(
      og_ws, wT + 4 * (DZc * DHCc), b2, out);
}